// Round 10
// baseline (52.296 us; speedup 1.0000x reference)
//
#include <hip/hip_runtime.h>
#include <stdint.h>

// FlagBagEncoder: out[t,:] = mean over {k : flags[t,k] > 0.5} of W[k,:], zeros if empty.
// T=100000, K=512, D=64, fp32 in/out.
//
// v10: FUSED stream+MFMA loop (no phases, no mask exchange). R9 showed B must be
// in LDS; R8's model says the remaining ~9 us is phase M's 1.6 MB/CU LDS burst
// happening after the barrier (un-overlapped tail). Fix: per k-step do
// {2 flag loads | 4 LDS B reads | pack | 4 MFMA} in one barrier-free loop so the
// LDS/MFMA work hides under the HBM stream (R4/R5 proved the stream rate is
// access-pattern-insensitive, so lane (m,kq) loads its own A data directly --
// no exchange needed). Keeps v7/v8: 1024-thr blocks, 64 KB LDS -> 2 blocks/CU =
// 32 waves/CU, grid 512, first stream loads issued before the one staging
// barrier. Staging is a pure uint4 copy from prepacked g_bfrag (prep kernel owns
// the bf16 convert). VGPR diet targets <=64 (the 2-blocks/CU cliff).
// k-map (identical for A and B, permutation cancels): k = 128*kq + 8*s + e.

#define T_ROWS 100000
#define K_FLAGS 512
#define D_DIM 64
#define TILES (T_ROWS / 16)   // 6250, exact

typedef __attribute__((ext_vector_type(4))) float f32x4;
typedef __attribute__((ext_vector_type(8))) short bf16x8;

// 16 k-steps x 4 n-tiles x 64 lanes x 4 dwords = 64 KB of prepacked B fragments.
__device__ uint32_t g_bfrag[16 * 4 * 64 * 4];

__device__ __forceinline__ uint32_t f32_to_bf16_rne(float f) {
  union { float f; uint32_t u; } v; v.f = f;
  uint32_t u = v.u;
  return (u + 0x7FFFu + ((u >> 16) & 1u)) >> 16;
}

// layout: g_bfrag[E], E = s*256 + nt*64 + lane (uint4 each)
// lane l: col n = (l&15)+16*nt ; k = 128*(l>>4) + 8*s + e ; dword j = elems (2j,2j+1) lo|hi
__global__ void prep_b_kernel(const float* __restrict__ W) {
  int E = blockIdx.x * blockDim.x + threadIdx.x;
  if (E >= 16 * 4 * 64) return;
  int lane = E & 63;
  int nt   = (E >> 6) & 3;
  int s    = E >> 8;
  int n    = (lane & 15) + 16 * nt;
  int kb   = 128 * (lane >> 4) + 8 * s;
  uint32_t r[4];
#pragma unroll
  for (int j = 0; j < 4; ++j) {
    uint32_t lo = f32_to_bf16_rne(W[(size_t)(kb + 2 * j    ) * D_DIM + n]);
    uint32_t hi = f32_to_bf16_rne(W[(size_t)(kb + 2 * j + 1) * D_DIM + n]);
    r[j] = lo | (hi << 16);
  }
  *reinterpret_cast<uint4*>(&g_bfrag[(size_t)E * 4]) = make_uint4(r[0], r[1], r[2], r[3]);
}

__global__ __launch_bounds__(1024, 8) void flagbag_kernel(const float* __restrict__ flags,
                                                          float* __restrict__ out) {
  __shared__ uint4 sB[16 * 4 * 64];   // 64 KB B-fragment table, layout == g_bfrag

  const int tid  = threadIdx.x;
  const int lane = tid & 63;
  const int wave = tid >> 6;
  const int tile = wave * 512 + (int)blockIdx.x;   // grid = 512 blocks exactly
  const bool active = (tile < TILES);
  const int t0 = (active ? tile : TILES - 1) * 16;  // clamp: safe redundant loads

  const int m  = lane & 15;   // A row within tile / output col within n-tile
  const int kq = lane >> 4;   // k quarter: this lane covers k in [128kq, 128kq+128)

  // lane-private flag window: row m, 8 floats per step at 128*kq + 8*s
  const float* ft = flags + (size_t)(t0 + m) * K_FLAGS + 128 * kq;

  // ---- prologue: start the HBM stream at cycle 0 (steps 0 and 1) ----
  f32x4 fa  = *reinterpret_cast<const f32x4*>(ft + 0);
  f32x4 fb  = *reinterpret_cast<const f32x4*>(ft + 4);
  f32x4 fan = *reinterpret_cast<const f32x4*>(ft + 8);
  f32x4 fbn = *reinterpret_cast<const f32x4*>(ft + 12);

  // ---- stage prepacked B table into LDS (pure copy, L2-hot source) ----
  {
    const uint4* gb = reinterpret_cast<const uint4*>(g_bfrag);
#pragma unroll
    for (int p = 0; p < 4; ++p) sB[tid + p * 1024] = gb[tid + p * 1024];
  }
  __syncthreads();   // only barrier in the kernel
  if (!active) return;

  f32x4 acc[4];
#pragma unroll
  for (int nt = 0; nt < 4; ++nt) acc[nt] = (f32x4){0.f, 0.f, 0.f, 0.f};
  int cnt = 0;

  // ---- fused loop: stream | LDS B | pack | MFMA, barrier-free ----
#pragma unroll
  for (int s = 0; s < 16; ++s) {
    f32x4 fa2, fb2;
    if (s + 2 < 16) {   // compile-time under full unroll
      fa2 = *reinterpret_cast<const f32x4*>(ft + 8 * (s + 2));
      fb2 = *reinterpret_cast<const f32x4*>(ft + 8 * (s + 2) + 4);
    }

    uint4 bc[4];
#pragma unroll
    for (int nt = 0; nt < 4; ++nt) bc[nt] = sB[s * 256 + nt * 64 + lane];

    bf16x8 af;
#pragma unroll
    for (int j = 0; j < 4; ++j) {
      const bool sa = fa[j] > 0.5f;
      const bool sb = fb[j] > 0.5f;
      af[j]     = sa ? (short)0x3F80 : (short)0;
      af[j + 4] = sb ? (short)0x3F80 : (short)0;
      cnt += sa ? 1 : 0;
      cnt += sb ? 1 : 0;
    }

#pragma unroll
    for (int nt = 0; nt < 4; ++nt)
      acc[nt] = __builtin_amdgcn_mfma_f32_16x16x32_bf16(
          af, *reinterpret_cast<const bf16x8*>(&bc[nt]), acc[nt], 0, 0, 0);

    fa = fan; fb = fbn; fan = fa2; fbn = fb2;
  }

  // full row-m count: lanes {m, m+16, m+32, m+48} hold disjoint k-quarters
  cnt += __shfl_xor(cnt, 16);
  cnt += __shfl_xor(cnt, 32);
  const float inv = (cnt > 0) ? (1.0f / (float)cnt) : 0.0f;

  // ---- epilogue: C/D layout col = lane&15, row = kq*4 + reg ----
#pragma unroll
  for (int r = 0; r < 4; ++r) {
    const int row = kq * 4 + r;
    const float invr = __shfl(inv, row);   // lane 'row' holds that row's count
    float* orow = out + (size_t)(t0 + row) * D_DIM + m;
#pragma unroll
    for (int nt = 0; nt < 4; ++nt)
      orow[16 * nt] = acc[nt][r] * invr;
  }
}

extern "C" void kernel_launch(void* const* d_in, const int* in_sizes, int n_in,
                              void* d_out, int out_size, void* d_ws, size_t ws_size,
                              hipStream_t stream) {
  const float* flags = (const float*)d_in[0];
  const float* W     = (const float*)d_in[1];
  float* out         = (float*)d_out;

  hipLaunchKernelGGL(prep_b_kernel, dim3(16), dim3(256), 0, stream, W);
  hipLaunchKernelGGL(flagbag_kernel, dim3(512), dim3(1024), 0, stream, flags, out);
}

// Round 11
// 47.311 us; speedup vs baseline: 1.1054x; 1.1054x over previous
//
#include <hip/hip_runtime.h>
#include <stdint.h>

// FlagBagEncoder: out[t,:] = mean over {k : flags[t,k] > 0.5} of W[k,:], zeros if empty.
// T=100000, K=512, D=64, fp32 in/out.
//
// v11: v8 structure (row-sequential per-wave streams, 1024-thr blocks, 32
// waves/CU, stream-first then W->sB convert, ONE barrier, then MFMA) with
// PAIR-SPLIT 32-row tiles to halve the post-barrier LDS tail:
//   - tile = 32 rows; wave A streams rows 0-15, wave B rows 16-31 (stream
//     pattern per wave identical to v8 -- R10 proved it must stay).
//   - both waves write mask bytes to a shared 2-KB sM region (ordered by the
//     one existing __syncthreads).
//   - phase M: mfma_f32_32x32x16_bf16 (fragments/C-D verified by R2's pass),
//     n-split: wave A = cols 0-31, wave B = cols 32-63. B-LDS reads per wave
//     drop 64KB -> 32KB; MFMA count halves.
// k-map (identical for A and B, permutation cancels): k = 16s + 8*(l>>5) + e.

#define T_ROWS 100000
#define K_FLAGS 512
#define D_DIM 64
#define TILES32 (T_ROWS / 32)   // 3125, exact

typedef __attribute__((ext_vector_type(4)))  float f32x4;
typedef __attribute__((ext_vector_type(16))) float f32x16;
typedef __attribute__((ext_vector_type(8)))  short bf16x8;

__device__ __forceinline__ uint32_t f32_to_bf16_rne(float f) {
  union { float f; uint32_t u; } v; v.f = f;
  uint32_t u = v.u;
  return (u + 0x7FFFu + ((u >> 16) & 1u)) >> 16;
}

__global__ __launch_bounds__(1024, 8) void flagbag_kernel(const float* __restrict__ flags,
                                                          const float* __restrict__ W,
                                                          float* __restrict__ out) {
  // B table: E = s*128 + nt*64 + lane (uint4 = 8 bf16). 32 steps x 2 nt -> 64 KB.
  __shared__ uint4 sB[32 * 2 * 64];
  // per-pair mask exchange: 512 dwords (2 KB) x 8 pairs = 16 KB. Total LDS 80 KB.
  __shared__ uint32_t sM[8][512];

  const int tid   = threadIdx.x;
  const int lane  = tid & 63;
  const int wave  = tid >> 6;
  const int pairv = wave >> 1;
  const int mate  = wave & 1;            // A=0: rows 0-15 / cols 0-31 ; B=1: rows 16-31 / cols 32-63
  const int slot  = pairv * 512 + (int)blockIdx.x;   // 8 pairs/block x 512 blocks = 4096 slots
  const bool active = (slot < TILES32);
  const int t0 = (active ? slot : 0) * 32;

  // ---- phase L FIRST: row-sequential contiguous stream of this wave's 16 rows ----
  if (active) {
    const float* ft = flags + (size_t)(t0 + 16 * mate) * K_FLAGS + lane * 8;

    uint32_t D0 = 0, D1 = 0, D2 = 0, D3 = 0;   // local rows 0-3 / 4-7 / 8-11 / 12-15
    f32x4 ra[4], rb[4];
#pragma unroll
    for (int r = 0; r < 3; ++r) {
      ra[r] = *reinterpret_cast<const f32x4*>(ft + r * K_FLAGS);
      rb[r] = *reinterpret_cast<const f32x4*>(ft + r * K_FLAGS + 4);
    }
#pragma unroll
    for (int r = 0; r < 16; ++r) {
      if (r + 3 < 16) {   // compile-time under full unroll
        ra[(r + 3) & 3] = *reinterpret_cast<const f32x4*>(ft + (r + 3) * K_FLAGS);
        rb[(r + 3) & 3] = *reinterpret_cast<const f32x4*>(ft + (r + 3) * K_FLAGS + 4);
      }
      const f32x4 a = ra[r & 3], b = rb[r & 3];
      uint32_t byte = 0;
#pragma unroll
      for (int j = 0; j < 4; ++j) {
        byte |= (a[j] > 0.5f) ? (1u << j)       : 0u;
        byte |= (b[j] > 0.5f) ? (1u << (j + 4)) : 0u;
      }
      const uint32_t sh = byte << ((r & 3) * 8);
      if ((r >> 2) == 0) D0 |= sh;
      else if ((r >> 2) == 1) D1 |= sh;
      else if ((r >> 2) == 2) D2 |= sh;
      else D3 |= sh;
    }

    // exchange: dword (region*256 + j*64 + (x ^ 4j ^ 16*region)) holds local rows
    // 4j..4j+3 (one byte each) of col-slice x, region = mate. Bijective in x.
    uint32_t* sMp = sM[pairv];
    const int xr = 16 * mate;
    sMp[mate * 256 + 0 * 64 + (lane ^ 0  ^ xr)] = D0;
    sMp[mate * 256 + 1 * 64 + (lane ^ 4  ^ xr)] = D1;
    sMp[mate * 256 + 2 * 64 + (lane ^ 8  ^ xr)] = D2;
    sMp[mate * 256 + 3 * 64 + (lane ^ 12 ^ xr)] = D3;
  }

  // ---- W -> bf16 fragment table (overlaps other waves' streams) ----
#pragma unroll
  for (int p = 0; p < 4; ++p) {
    const int E   = tid + p * 1024;
    const int ln  = E & 63;
    const int ntc = (E >> 6) & 1;
    const int s   = E >> 7;
    const int n   = (ln & 31) + 32 * ntc;
    const int kb  = 16 * s + 8 * (ln >> 5);
    uint32_t r[4];
#pragma unroll
    for (int j = 0; j < 4; ++j) {
      uint32_t lo = f32_to_bf16_rne(W[(size_t)(kb + 2 * j    ) * D_DIM + n]);
      uint32_t hi = f32_to_bf16_rne(W[(size_t)(kb + 2 * j + 1) * D_DIM + n]);
      r[j] = lo | (hi << 16);
    }
    sB[E] = make_uint4(r[0], r[1], r[2], r[3]);
  }
  __syncthreads();   // only barrier: orders sB AND the pair's sM
  if (!active) return;

  // ---- phase M: 32x32x16 MFMA, n-split across the pair ----
  const int lr     = lane & 31;   // mask row (and output col)
  const int kg     = lane >> 5;   // k-group: k = 16s + 8kg + e
  const int region = lr >> 4;
  const int mj     = (lr & 15) >> 2;
  const int mb     = lr & 3;
  const int baseDw = region * 256 + mj * 64;
  const int X      = (4 * mj) ^ (16 * region);
  const uint8_t* sMb = reinterpret_cast<const uint8_t*>(sM[pairv]);

  f32x16 acc;
#pragma unroll
  for (int i = 0; i < 16; ++i) acc[i] = 0.f;
  int cnt = 0;

  uint4 bc = sB[mate * 64 + lane];
#pragma unroll
  for (int s = 0; s < 32; ++s) {
    uint4 bn;
    if (s + 1 < 32) bn = sB[(s + 1) * 128 + mate * 64 + lane];

    // mask byte c = 2s + kg of row lr -> k bits [16s+8kg, +8)
    const uint32_t byte = sMb[(size_t)(baseDw + ((2 * s + kg) ^ X)) * 4 + mb];
    cnt += __popc(byte);

    bf16x8 af;
#pragma unroll
    for (int e = 0; e < 8; ++e) af[e] = ((byte >> e) & 1u) ? (short)0x3F80 : (short)0;

    acc = __builtin_amdgcn_mfma_f32_32x32x16_bf16(
        af, *reinterpret_cast<const bf16x8*>(&bc), acc, 0, 0, 0);
    bc = bn;
  }

  // lanes lr and lr+32 hold the two k-halves of row lr
  cnt += __shfl_xor(cnt, 32);
  const float inv = (cnt > 0) ? (1.0f / (float)cnt) : 0.0f;

  // C/D layout (R2-verified): col = lane&31, row = (reg&3) + 8*(reg>>2) + 4*kg
#pragma unroll
  for (int reg = 0; reg < 16; ++reg) {
    const int row = (reg & 3) + 8 * (reg >> 2) + 4 * kg;
    const float invr = __shfl(inv, row);   // lane 'row' holds that row's full count
    out[(size_t)(t0 + row) * D_DIM + lr + 32 * mate] = acc[reg] * invr;
  }
}

extern "C" void kernel_launch(void* const* d_in, const int* in_sizes, int n_in,
                              void* d_out, int out_size, void* d_ws, size_t ws_size,
                              hipStream_t stream) {
  const float* flags = (const float*)d_in[0];
  const float* W     = (const float*)d_in[1];
  float* out         = (float*)d_out;

  hipLaunchKernelGGL(flagbag_kernel, dim3(512), dim3(1024), 0, stream, flags, W, out);
}

// Round 12
// 46.891 us; speedup vs baseline: 1.1153x; 1.0089x over previous
//
#include <hip/hip_runtime.h>
#include <stdint.h>

// FlagBagEncoder: out[t,:] = mean over {k : flags[t,k] > 0.5} of W[k,:], zeros if empty.
// T=100000, K=512, D=64, fp32 in/out.
//
// v12: v8 with the barrier MOVED BEFORE the stream. v8's post-stream barrier
// forced every wave's phase M to start at max(block's 16 stream-ends), bunching
// ~1 MB/block of LDS B-reads + the store burst into a dead tail. Now: sB is a
// pure uint4 copy from prepacked g_bfrag (prep kernel owns the bf16 convert),
// __syncthreads right after staging (~1 us, flag prologue loads already in
// flight), then stream -> wave-private sM exchange (lgkmcnt ordering only, v9-
// proven) -> phase M -> stores, with NO further sync: each wave's phase M starts
// when ITS stream ends, staggered by HBM jitter, overlapping remaining streams.
// Unchanged from v8: stream pattern, exchange, phase M, epilogue, 1024-thr
// blocks (32 waves/CU, LDS 80 KB -> 2 blocks/CU), grid 512, tile = wave*512+bid.
// k-map (identical for A and B, permutation cancels): k = 128*kq + 8*s + e.

#define T_ROWS 100000
#define K_FLAGS 512
#define D_DIM 64
#define TILES (T_ROWS / 16)   // 6250, exact

typedef __attribute__((ext_vector_type(4))) float f32x4;
typedef __attribute__((ext_vector_type(8))) short bf16x8;

// 16 k-steps x 4 n-tiles x 64 lanes x 4 dwords = 64 KB of prepacked B fragments.
__device__ uint32_t g_bfrag[16 * 4 * 64 * 4];

__device__ __forceinline__ uint32_t f32_to_bf16_rne(float f) {
  union { float f; uint32_t u; } v; v.f = f;
  uint32_t u = v.u;
  return (u + 0x7FFFu + ((u >> 16) & 1u)) >> 16;
}

// layout: g_bfrag[E], E = s*256 + nt*64 + lane (uint4 each)
// lane l: col n = (l&15)+16*nt ; k = 128*(l>>4) + 8*s + e ; dword j = elems (2j,2j+1) lo|hi
__global__ void prep_b_kernel(const float* __restrict__ W) {
  int E = blockIdx.x * blockDim.x + threadIdx.x;
  if (E >= 16 * 4 * 64) return;
  int lane = E & 63;
  int nt   = (E >> 6) & 3;
  int s    = E >> 8;
  int n    = (lane & 15) + 16 * nt;
  int kb   = 128 * (lane >> 4) + 8 * s;
  uint32_t r[4];
#pragma unroll
  for (int j = 0; j < 4; ++j) {
    uint32_t lo = f32_to_bf16_rne(W[(size_t)(kb + 2 * j    ) * D_DIM + n]);
    uint32_t hi = f32_to_bf16_rne(W[(size_t)(kb + 2 * j + 1) * D_DIM + n]);
    r[j] = lo | (hi << 16);
  }
  *reinterpret_cast<uint4*>(&g_bfrag[(size_t)E * 4]) = make_uint4(r[0], r[1], r[2], r[3]);
}

__global__ __launch_bounds__(1024, 8) void flagbag_kernel(const float* __restrict__ flags,
                                                          float* __restrict__ out) {
  __shared__ uint4 sB[16 * 4 * 64];     // 64 KB B-fragment table, layout == g_bfrag
  __shared__ uint32_t sM[16][256];      // 1 KB per wave mask exchange (wave-private)

  const int tid  = threadIdx.x;
  const int lane = tid & 63;
  const int wave = tid >> 6;
  const int tile = wave * 512 + (int)blockIdx.x;   // grid = 512 blocks exactly
  const bool active = (tile < TILES);
  const int t0 = (active ? tile : 0) * 16;         // clamp: safe redundant loads

  // ---- issue the stream prologue FIRST (steps 0..2 of the depth-4 ring) ----
  const float* ft = flags + (size_t)t0 * K_FLAGS + lane * 8;
  f32x4 ra[4], rb[4];
#pragma unroll
  for (int r = 0; r < 3; ++r) {
    ra[r] = *reinterpret_cast<const f32x4*>(ft + r * K_FLAGS);
    rb[r] = *reinterpret_cast<const f32x4*>(ft + r * K_FLAGS + 4);
  }

  // ---- stage prepacked B table into LDS (pure copy, L2-hot source) ----
  {
    const uint4* gb = reinterpret_cast<const uint4*>(g_bfrag);
#pragma unroll
    for (int p = 0; p < 4; ++p) sB[tid + p * 1024] = gb[tid + p * 1024];
  }
  __syncthreads();   // ONLY barrier in the kernel -- before the stream
  if (!active) return;

  // ---- phase L: row-sequential contiguous read of the 32-KB tile ----
  uint32_t D0 = 0, D1 = 0, D2 = 0, D3 = 0;   // rows 0-3 / 4-7 / 8-11 / 12-15
#pragma unroll
  for (int r = 0; r < 16; ++r) {
    if (r + 3 < 16) {   // compile-time under full unroll
      ra[(r + 3) & 3] = *reinterpret_cast<const f32x4*>(ft + (r + 3) * K_FLAGS);
      rb[(r + 3) & 3] = *reinterpret_cast<const f32x4*>(ft + (r + 3) * K_FLAGS + 4);
    }
    const f32x4 a = ra[r & 3], b = rb[r & 3];
    uint32_t byte = 0;
#pragma unroll
    for (int j = 0; j < 4; ++j) {
      byte |= (a[j] > 0.5f) ? (1u << j)       : 0u;
      byte |= (b[j] > 0.5f) ? (1u << (j + 4)) : 0u;
    }
    const uint32_t sh = byte << ((r & 3) * 8);
    if ((r >> 2) == 0) D0 |= sh;
    else if ((r >> 2) == 1) D1 |= sh;
    else if ((r >> 2) == 2) D2 |= sh;
    else D3 |= sh;
  }

  uint32_t* sMw = sM[wave];
  sMw[0 * 64 + (lane ^ 0)]  = D0;
  sMw[1 * 64 + (lane ^ 4)]  = D1;
  sMw[2 * 64 + (lane ^ 8)]  = D2;
  sMw[3 * 64 + (lane ^ 12)] = D3;
  // wave-internal LDS write->read: compiler inserts the lgkmcnt wait; no block sync.

  // ---- phase M: MFMA over the exchanged mask, B from LDS (starts when MY stream ends) ----
  const int m  = lane & 15;   // A row within tile / output col within n-tile
  const int kq = lane >> 4;
  const int mj = m >> 2, mb = m & 3;
  const int m4 = 4 * mj;
  const uint8_t* sMb = reinterpret_cast<const uint8_t*>(sMw);
  const int C = 4 * (mj * 64 + 16 * kq) + mb;

  const uint4* sbl = &sB[lane];
  f32x4 acc[4];
#pragma unroll
  for (int nt = 0; nt < 4; ++nt) acc[nt] = (f32x4){0.f, 0.f, 0.f, 0.f};

  uint4 bc[4], bn[4];
#pragma unroll
  for (int nt = 0; nt < 4; ++nt) bc[nt] = sbl[nt * 64];

  int cnt = 0;
#pragma unroll
  for (int s = 0; s < 16; ++s) {
    if (s + 1 < 16) {
#pragma unroll
      for (int nt = 0; nt < 4; ++nt) bn[nt] = sbl[((s + 1) * 4 + nt) * 64];
    }
    const uint32_t byte = sMb[C + 4 * (s ^ m4)];   // 8 k-bits of row m, k=128kq+8s+e
    cnt += __popc(byte);
    bf16x8 af;
#pragma unroll
    for (int e = 0; e < 8; ++e) af[e] = ((byte >> e) & 1u) ? (short)0x3F80 : (short)0;

#pragma unroll
    for (int nt = 0; nt < 4; ++nt)
      acc[nt] = __builtin_amdgcn_mfma_f32_16x16x32_bf16(
          af, *reinterpret_cast<const bf16x8*>(&bc[nt]), acc[nt], 0, 0, 0);

#pragma unroll
    for (int nt = 0; nt < 4; ++nt) bc[nt] = bn[nt];
  }

  // full row-m count: lanes {m, m+16, m+32, m+48} hold disjoint k-quarters
  cnt += __shfl_xor(cnt, 16);
  cnt += __shfl_xor(cnt, 32);
  const float inv = (cnt > 0) ? (1.0f / (float)cnt) : 0.0f;

  // ---- epilogue: C/D layout col = lane&15, row = kq*4 + reg ----
#pragma unroll
  for (int r = 0; r < 4; ++r) {
    const int row = kq * 4 + r;
    const float invr = __shfl(inv, row);   // lane 'row' holds that row's count
    float* orow = out + (size_t)(t0 + row) * D_DIM + m;
#pragma unroll
    for (int nt = 0; nt < 4; ++nt)
      orow[16 * nt] = acc[nt][r] * invr;
  }
}

extern "C" void kernel_launch(void* const* d_in, const int* in_sizes, int n_in,
                              void* d_out, int out_size, void* d_ws, size_t ws_size,
                              hipStream_t stream) {
  const float* flags = (const float*)d_in[0];
  const float* W     = (const float*)d_in[1];
  float* out         = (float*)d_out;

  hipLaunchKernelGGL(prep_b_kernel, dim3(16), dim3(256), 0, stream, W);
  hipLaunchKernelGGL(flagbag_kernel, dim3(512), dim3(1024), 0, stream, flags, out);
}